// Round 4
// baseline (410.752 us; speedup 1.0000x reference)
//
#include <hip/hip_runtime.h>

// DST-I spectral Helmholtz solver, NZ=4, NX=NY=2048.
// psi = Cm2l · [ S (S (Cl2m·q) S ⊘ H) S  + alpha·homsol ],  S = DST-I matrix (symmetric, orthonormal)
// GEMMs: 256x256 8-wave, faithful m201 8-phase schedule: read-ahead + counted lgkm/vmcnt.

typedef __attribute__((ext_vector_type(8))) short bf16x8;
typedef __attribute__((ext_vector_type(4))) float f32x4;
typedef __attribute__((ext_vector_type(8))) unsigned short ushort8;

#define LDS_SPACE __attribute__((address_space(3)))
#define GLB_SPACE __attribute__((address_space(1)))

__device__ __forceinline__ void gld_lds16(const unsigned short* g, unsigned short* l) {
  __builtin_amdgcn_global_load_lds((const GLB_SPACE void*)g, (LDS_SPACE void*)l, 16, 0, 0);
}

__device__ __forceinline__ bf16x8 ds_read128o(const LDS_SPACE char* p, int imm) {
  bf16x8 r;
  asm volatile("ds_read_b128 %0, %1 offset:%2" : "=v"(r) : "v"(p), "i"(imm));
  return r;
}

__device__ __forceinline__ unsigned short f2b(float f) {
  union { float f; unsigned u; } v; v.f = f;
  unsigned r = (v.u + 0x7fffu + ((v.u >> 16) & 1u)) >> 16;  // RNE
  return (unsigned short)r;
}
__device__ __forceinline__ float b2f(unsigned short u) {
  union { unsigned u; float f; } v; v.u = ((unsigned)u) << 16;
  return v.f;
}

#define LGKM(N) asm volatile("s_waitcnt lgkmcnt(" #N ")" ::: "memory")
#define VMC(N)  asm volatile("s_waitcnt vmcnt(" #N ")" ::: "memory")
#define BAR()   __builtin_amdgcn_s_barrier()
#define SB0()   __builtin_amdgcn_sched_barrier(0)
#define PRIO1() __builtin_amdgcn_s_setprio(1)
#define PRIO0() __builtin_amdgcn_s_setprio(0)

// ---- DST-I matrix, padded to 2048x2048 (row/col 2047 zero), bf16 ----
__global__ __launch_bounds__(256)
void dst_kernel(unsigned short* __restrict__ Sb) {
  const int idx = blockIdx.x * 256 + threadIdx.x;
  const int j = idx & 2047, i = idx >> 11;
  float v = 0.f;
  if (i < 2047 && j < 2047) {
    const int ph = ((i + 1) * (j + 1)) & 4095;  // exact phase mod 2*pi
    v = 0.03125f * sinf(3.14159265358979323846f * (float)ph * (1.0f / 2048.0f));
  }
  Sb[idx] = f2b(v);
}

// ---- layer->mode mix: P[m] = sum_l Cl2m[m,l] q[l], padded to 2048^2, bf16 ----
__global__ __launch_bounds__(256)
void mix_kernel(const float* __restrict__ q, const float* __restrict__ Cl2m,
                unsigned short* __restrict__ P) {
  const int idx = blockIdx.x * 256 + threadIdx.x;
  const int y = idx & 2047, x = idx >> 11;
  float c[16];
#pragma unroll
  for (int i = 0; i < 16; ++i) c[i] = Cl2m[i];
  float v0 = 0.f, v1 = 0.f, v2 = 0.f, v3 = 0.f;
  if (x < 2047 && y < 2047) {
    const size_t o = (size_t)x * 2047 + y;
    const float q0 = q[o];
    const float q1 = q[o + 4190209u];
    const float q2 = q[o + 2u * 4190209u];
    const float q3 = q[o + 3u * 4190209u];
    v0 = c[0]  * q0 + c[1]  * q1 + c[2]  * q2 + c[3]  * q3;
    v1 = c[4]  * q0 + c[5]  * q1 + c[6]  * q2 + c[7]  * q3;
    v2 = c[8]  * q0 + c[9]  * q1 + c[10] * q2 + c[11] * q3;
    v3 = c[12] * q0 + c[13] * q1 + c[14] * q2 + c[15] * q3;
  }
  P[idx]                 = f2b(v0);
  P[idx + 4194304u]      = f2b(v1);
  P[idx + 2u * 4194304u] = f2b(v2);
  P[idx + 3u * 4194304u] = f2b(v3);
}

// ---- batched per-mode 2048x2048 bf16 transpose (64x64 LDS tiles) ----
__global__ __launch_bounds__(256)
void transpose_bf16(const unsigned short* __restrict__ in, unsigned short* __restrict__ out) {
  __shared__ unsigned short tile[64][65];
  const size_t pb = (size_t)blockIdx.z * (2048u * 2048u);
  const unsigned short* ip = in + pb;
  unsigned short* op = out + pb;
  const int r0 = blockIdx.y * 64, c0 = blockIdx.x * 64;
  const int t = threadIdx.x;
  const int rr = t >> 3;
  const int cc = (t & 7) * 8;
#pragma unroll
  for (int ch = 0; ch < 2; ++ch) {
    const int r = ch * 32 + rr;
    ushort8 v = *(const ushort8*)&ip[(size_t)(r0 + r) * 2048 + c0 + cc];
#pragma unroll
    for (int j = 0; j < 8; ++j) tile[r][cc + j] = v[j];
  }
  __syncthreads();
#pragma unroll
  for (int ch = 0; ch < 2; ++ch) {
    const int r = ch * 32 + rr;
    ushort8 v;
#pragma unroll
    for (int j = 0; j < 8; ++j) v[j] = tile[cc + j][r];
    *(ushort8*)&op[(size_t)(c0 + r) * 2048 + r0 + cc] = v;
  }
}

// ---- GEMM: C[8192x2048] = A[8192x2048] * S (S symmetric), 256^2 tile, 8 waves ----
#define MFMA_BF16 __builtin_amdgcn_mfma_f32_16x16x32_bf16

#define QUAD(AF, BF, MB, NB)                                            \
  _Pragma("unroll")                                                     \
  for (int ks = 0; ks < 2; ++ks)                                        \
    _Pragma("unroll")                                                   \
    for (int m = 0; m < 4; ++m)                                         \
      _Pragma("unroll")                                                 \
      for (int n = 0; n < 2; ++n)                                       \
        acc[MB + m][NB + n] = MFMA_BF16(AF[m][ks], BF[n][ks], acc[MB + m][NB + n], 0, 0, 0);

#define RD_A(DST, BASE, EXTRA)                                          \
  _Pragma("unroll")                                                     \
  for (int m = 0; m < 4; ++m)                                           \
    _Pragma("unroll")                                                   \
    for (int ks = 0; ks < 2; ++ks)                                      \
      DST[m][ks] = ds_read128o(BASE[ks], m * 2048 + (EXTRA));

#define RD_B(DST, BASE, EXTRA)                                          \
  _Pragma("unroll")                                                     \
  for (int n = 0; n < 2; ++n)                                           \
    _Pragma("unroll")                                                   \
    for (int ks = 0; ks < 2; ++ks)                                      \
      DST[n][ks] = ds_read128o(BASE[ks], n * 2048 + (EXTRA));

template <int EPI>
__global__ __launch_bounds__(512, 2)
void gemm256(const unsigned short* __restrict__ A, const unsigned short* __restrict__ S,
             unsigned short* __restrict__ Cb, const float* __restrict__ H,
             float* __restrict__ sums) {
  __shared__ __align__(16) char lds[131072];  // buf0 @0, buf1 @65536; B-region +32768
  const int bid = blockIdx.x;
  const int swz = (bid & 7) * 32 + (bid >> 3);      // XCD-bijective (256 % 8 == 0)
  const int bm = swz >> 3, bn = swz & 7;
  const int tid = threadIdx.x;
  const int lane = tid & 63, wave = tid >> 6;
  const int wr = wave >> 2, wc = wave & 3;          // 2 x 4 wave grid
  const int lr = lane & 15, kg = lane >> 4;
  const int x7 = lr & 7;

  const unsigned short* gA = A + (size_t)bm * 256 * 2048;
  const unsigned short* gB = S + (size_t)bn * 256 * 2048;

  // staging: 16B slot ps = tid + i*512; row = ps>>3; global col16 = (ps&7)^(row&7)
  const int row0 = tid >> 3;
  const int slot = (tid & 7) ^ (row0 & 7);

  auto stageA = [&](int kt, int buf) {
    char* lc = lds + buf * 65536;
    const size_t ko = (size_t)kt * 64 + slot * 8;
#pragma unroll
    for (int i = 0; i < 4; ++i)
      gld_lds16(gA + (size_t)(row0 + i * 64) * 2048 + ko,
                (unsigned short*)(lc + (tid + i * 512) * 16));
  };
  auto stageB = [&](int kt, int buf) {
    char* lc = lds + buf * 65536 + 32768;
    const size_t ko = (size_t)kt * 64 + slot * 8;
#pragma unroll
    for (int i = 0; i < 4; ++i)
      gld_lds16(gB + (size_t)(row0 + i * 64) * 2048 + ko,
                (unsigned short*)(lc + (tid + i * 512) * 16));
  };

  // lane-invariant LDS read bases (per K-slice ks); all tile/frag offsets are immediates
  const int arow = wr * 128 + lr;   // + m*16
  const int brow = wc * 64 + lr;    // + n*16
  const LDS_SPACE char* aU[2];
  const LDS_SPACE char* bU[2];
  const LDS_SPACE char* aV[2];
  const LDS_SPACE char* bV[2];
#pragma unroll
  for (int ks = 0; ks < 2; ++ks) {
    const int swA = (((ks * 4 + kg) ^ x7) << 4);
    aU[ks] = (const LDS_SPACE char*)(lds) + arow * 128 + swA;
    bU[ks] = (const LDS_SPACE char*)(lds) + 32768 + brow * 128 + swA;
    aV[ks] = aU[ks] + 65536;
    bV[ks] = bU[ks] + 65536;
  }

  f32x4 acc[8][4];
#pragma unroll
  for (int m = 0; m < 8; ++m)
#pragma unroll
    for (int n = 0; n < 4; ++n) acc[m][n] = (f32x4){0.f, 0.f, 0.f, 0.f};

  bf16x8 al[4][2], ah[4][2], bl[2][2], bh[2][2];

  // ---- prologue: stage tiles 0,1; full drain once; preload al,bl of tile 0
  stageA(0, 0); stageB(0, 0); stageA(1, 1); stageB(1, 1);
  VMC(0);
  BAR();
  RD_A(al, aU, 0);
  RD_B(bl, bU, 0);

  for (int i = 0; i < 16; ++i) {
    const int wk = (2 * i + 2 < 32) ? 2 * i + 2 : 31;   // next even tile -> buf0
    const int xk = (2 * i + 3 < 32) ? 2 * i + 3 : 31;   // next odd tile  -> buf1

    // P1: issue bh_u | Q00_u(al,bl)
    RD_B(bh, bU, 4096);
    BAR(); LGKM(4); SB0();
    PRIO1(); QUAD(al, bl, 0, 0); PRIO0(); BAR();

    // P2: issue ah_u | Q01_u(al,bh)
    RD_A(ah, aU, 8192);
    BAR(); LGKM(8); SB0();
    PRIO1(); QUAD(al, bh, 0, 2); PRIO0(); BAR();

    // P3: vmcnt(4), issue al_v, stage A_w->buf0 | Q10_u(ah,bl)
    VMC(4);
    RD_A(al, aV, 0);
    stageA(wk, 0);
    BAR(); LGKM(8); SB0();
    PRIO1(); QUAD(ah, bl, 4, 0); PRIO0(); BAR();

    // P4: vmcnt(4), issue bl_v, stage B_w->buf0 | Q11_u(ah,bh)
    VMC(4);
    RD_B(bl, bV, 0);
    stageB(wk, 0);
    BAR(); SB0();
    PRIO1(); QUAD(ah, bh, 4, 2); PRIO0(); BAR();

    // P5: issue bh_v | Q00_v(al,bl)
    RD_B(bh, bV, 4096);
    BAR(); LGKM(4); SB0();
    PRIO1(); QUAD(al, bl, 0, 0); PRIO0(); BAR();

    // P6: issue ah_v | Q01_v(al,bh)
    RD_A(ah, aV, 8192);
    BAR(); LGKM(8); SB0();
    PRIO1(); QUAD(al, bh, 0, 2); PRIO0(); BAR();

    // P7: vmcnt(4), issue al_w (buf0), stage A_x->buf1 | Q10_v(ah,bl)
    VMC(4);
    RD_A(al, aU, 0);
    stageA(xk, 1);
    BAR(); LGKM(8); SB0();
    PRIO1(); QUAD(ah, bl, 4, 0); PRIO0(); BAR();

    // P8: vmcnt(4), issue bl_w (buf0), stage B_x->buf1 | Q11_v(ah,bh)
    VMC(4);
    RD_B(bl, bU, 0);
    stageB(xk, 1);
    BAR(); SB0();
    PRIO1(); QUAD(ah, bh, 4, 2); PRIO0(); BAR();
  }

  // drain the final read-ahead (values unused) before registers are reused
  LGKM(0); VMC(0);

  // ---- epilogue: C row = kg*4+j within fragment, col = lr
  float ssum = 0.f;
#pragma unroll
  for (int m = 0; m < 8; ++m) {
#pragma unroll
    for (int n = 0; n < 4; ++n) {
      const int col = bn * 256 + wc * 64 + n * 16 + lr;
#pragma unroll
      for (int j = 0; j < 4; ++j) {
        const int gr = bm * 256 + wr * 128 + m * 16 + kg * 4 + j;
        const float v = acc[m][n][j];
        if (EPI == 1) {
          const int ii = gr & 2047;
          float o = 0.f;
          if (ii < 2047 && col < 2047)
            o = v / H[((size_t)(gr >> 11) * 2047 + ii) * 2047 + col];
          Cb[(size_t)gr * 2048 + col] = f2b(o);
        } else {
          Cb[(size_t)gr * 2048 + col] = f2b(v);
          if (EPI == 2) ssum += v;
        }
      }
    }
  }
  if (EPI == 2) {
#pragma unroll
    for (int off = 32; off > 0; off >>= 1) ssum += __shfl_xor(ssum, off);
    if (lane == 0) atomicAdd(&sums[bm >> 3], ssum);
  }
}

// ---- final: un-pad, homogeneous correction, mode->layer mix ----
__global__ __launch_bounds__(256)
void final_kernel(const unsigned short* __restrict__ T5, const float* __restrict__ homsol,
                  const float* __restrict__ hm, const float* __restrict__ Cm2l,
                  const float* __restrict__ sums, float* __restrict__ out) {
  const int p = blockIdx.x * 256 + threadIdx.x;
  if (p >= 2049 * 2049) return;
  const int x = p / 2049, y = p - x * 2049;
  const bool interior = (x >= 1) && (x <= 2047) && (y >= 1) && (y <= 2047);
  float pm[4];
#pragma unroll
  for (int m = 0; m < 4; ++m) {
    float inner = 0.f;
    if (interior) inner = b2f(T5[(size_t)m * 4194304u + (size_t)(x - 1) * 2048 + (y - 1)]);
    const float alpha = -(sums[m] * (1.0f / 4194304.0f)) / hm[m];
    pm[m] = inner + alpha * homsol[(size_t)m * 4198401u + p];
  }
#pragma unroll
  for (int l = 0; l < 4; ++l) {
    out[(size_t)l * 4198401u + p] =
        Cm2l[l * 4 + 0] * pm[0] + Cm2l[l * 4 + 1] * pm[1] +
        Cm2l[l * 4 + 2] * pm[2] + Cm2l[l * 4 + 3] * pm[3];
  }
}

extern "C" void kernel_launch(void* const* d_in, const int* in_sizes, int n_in,
                              void* d_out, int out_size, void* d_ws, size_t ws_size,
                              hipStream_t stream) {
  const float* q     = (const float*)d_in[0];   // [4,2047,2047]
  const float* Cl2m  = (const float*)d_in[1];   // [4,4]
  const float* Cm2l  = (const float*)d_in[2];   // [4,4]
  const float* H     = (const float*)d_in[3];   // [4,2047,2047]
  const float* hom   = (const float*)d_in[4];   // [4,2049,2049]
  const float* hmean = (const float*)d_in[5];   // [4]
  float* out = (float*)d_out;

  char* ws = (char*)d_ws;
  unsigned short* P  = (unsigned short*)ws;                    // 33,554,432 B
  unsigned short* Q  = (unsigned short*)(ws + 33554432u);      // 33,554,432 B
  unsigned short* Sb = (unsigned short*)(ws + 67108864u);      //  8,388,608 B
  float* sums        = (float*)(ws + 75497472u);               //        16 B

  dst_kernel<<<16384, 256, 0, stream>>>(Sb);
  mix_kernel<<<16384, 256, 0, stream>>>(q, Cl2m, P);
  hipMemsetAsync(sums, 0, 16, stream);

  // Q1 = P * S            (DST along y)
  gemm256<0><<<256, 512, 0, stream>>>(P, Sb, Q, nullptr, nullptr);
  transpose_bf16<<<dim3(32, 32, 4), 256, 0, stream>>>(Q, P);
  // Q2 = (P * S) / H      (DST along x; H symmetric)
  gemm256<1><<<256, 512, 0, stream>>>(P, Sb, Q, H, nullptr);
  // P2 = Q2 * S           (inverse DST step 1)
  gemm256<0><<<256, 512, 0, stream>>>(Q, Sb, P, nullptr, nullptr);
  transpose_bf16<<<dim3(32, 32, 4), 256, 0, stream>>>(P, Q);
  // T5 = Q3 * S (+ per-mode sum for mean correction)
  gemm256<2><<<256, 512, 0, stream>>>(Q, Sb, P, nullptr, sums);

  final_kernel<<<16401, 256, 0, stream>>>(P, hom, hmean, Cm2l, sums, out);
}

// Round 5
// 394.956 us; speedup vs baseline: 1.0400x; 1.0400x over previous
//
#include <hip/hip_runtime.h>

// DST-I spectral Helmholtz solver, NZ=4, NX=NY=2048.
// psi = Cm2l · [ S (S (Cl2m·q) S ⊘ H) S  + alpha·homsol ],  S = DST-I matrix (symmetric, orthonormal)
// GEMMs: 256x256 8-wave, 32x32x16 MFMA, 1 barrier + 1 vmcnt(0) per K-tile, counted-lgkm pipeline.

typedef __attribute__((ext_vector_type(8))) short bf16x8;
typedef __attribute__((ext_vector_type(16))) float f32x16;
typedef __attribute__((ext_vector_type(8))) unsigned short ushort8;

#define LDS_SPACE __attribute__((address_space(3)))
#define GLB_SPACE __attribute__((address_space(1)))

__device__ __forceinline__ void gld_lds16(const unsigned short* g, unsigned short* l) {
  __builtin_amdgcn_global_load_lds((const GLB_SPACE void*)g, (LDS_SPACE void*)l, 16, 0, 0);
}

__device__ __forceinline__ bf16x8 ds_read128o(const LDS_SPACE char* p, int imm) {
  bf16x8 r;
  asm volatile("ds_read_b128 %0, %1 offset:%2" : "=v"(r) : "v"(p), "i"(imm));
  return r;
}

__device__ __forceinline__ unsigned short f2b(float f) {
  union { float f; unsigned u; } v; v.f = f;
  unsigned r = (v.u + 0x7fffu + ((v.u >> 16) & 1u)) >> 16;  // RNE
  return (unsigned short)r;
}
__device__ __forceinline__ float b2f(unsigned short u) {
  union { unsigned u; float f; } v; v.u = ((unsigned)u) << 16;
  return v.f;
}

#define LGKM(N) asm volatile("s_waitcnt lgkmcnt(" #N ")" ::: "memory")
#define VMC(N)  asm volatile("s_waitcnt vmcnt(" #N ")" ::: "memory")
#define BAR()   __builtin_amdgcn_s_barrier()
#define SB0()   __builtin_amdgcn_sched_barrier(0)
#define PRIO1() __builtin_amdgcn_s_setprio(1)
#define PRIO0() __builtin_amdgcn_s_setprio(0)

// ---- DST-I matrix, padded to 2048x2048 (row/col 2047 zero), bf16 ----
__global__ __launch_bounds__(256)
void dst_kernel(unsigned short* __restrict__ Sb) {
  const int idx = blockIdx.x * 256 + threadIdx.x;
  const int j = idx & 2047, i = idx >> 11;
  float v = 0.f;
  if (i < 2047 && j < 2047) {
    const int ph = ((i + 1) * (j + 1)) & 4095;  // exact phase mod 2*pi
    v = 0.03125f * sinf(3.14159265358979323846f * (float)ph * (1.0f / 2048.0f));
  }
  Sb[idx] = f2b(v);
}

// ---- layer->mode mix: P[m] = sum_l Cl2m[m,l] q[l], padded to 2048^2, bf16 ----
__global__ __launch_bounds__(256)
void mix_kernel(const float* __restrict__ q, const float* __restrict__ Cl2m,
                unsigned short* __restrict__ P) {
  const int idx = blockIdx.x * 256 + threadIdx.x;
  const int y = idx & 2047, x = idx >> 11;
  float c[16];
#pragma unroll
  for (int i = 0; i < 16; ++i) c[i] = Cl2m[i];
  float v0 = 0.f, v1 = 0.f, v2 = 0.f, v3 = 0.f;
  if (x < 2047 && y < 2047) {
    const size_t o = (size_t)x * 2047 + y;
    const float q0 = q[o];
    const float q1 = q[o + 4190209u];
    const float q2 = q[o + 2u * 4190209u];
    const float q3 = q[o + 3u * 4190209u];
    v0 = c[0]  * q0 + c[1]  * q1 + c[2]  * q2 + c[3]  * q3;
    v1 = c[4]  * q0 + c[5]  * q1 + c[6]  * q2 + c[7]  * q3;
    v2 = c[8]  * q0 + c[9]  * q1 + c[10] * q2 + c[11] * q3;
    v3 = c[12] * q0 + c[13] * q1 + c[14] * q2 + c[15] * q3;
  }
  P[idx]                 = f2b(v0);
  P[idx + 4194304u]      = f2b(v1);
  P[idx + 2u * 4194304u] = f2b(v2);
  P[idx + 3u * 4194304u] = f2b(v3);
}

// ---- batched per-mode 2048x2048 bf16 transpose (64x64 LDS tiles) ----
__global__ __launch_bounds__(256)
void transpose_bf16(const unsigned short* __restrict__ in, unsigned short* __restrict__ out) {
  __shared__ unsigned short tile[64][65];
  const size_t pb = (size_t)blockIdx.z * (2048u * 2048u);
  const unsigned short* ip = in + pb;
  unsigned short* op = out + pb;
  const int r0 = blockIdx.y * 64, c0 = blockIdx.x * 64;
  const int t = threadIdx.x;
  const int rr = t >> 3;
  const int cc = (t & 7) * 8;
#pragma unroll
  for (int ch = 0; ch < 2; ++ch) {
    const int r = ch * 32 + rr;
    ushort8 v = *(const ushort8*)&ip[(size_t)(r0 + r) * 2048 + c0 + cc];
#pragma unroll
    for (int j = 0; j < 8; ++j) tile[r][cc + j] = v[j];
  }
  __syncthreads();
#pragma unroll
  for (int ch = 0; ch < 2; ++ch) {
    const int r = ch * 32 + rr;
    ushort8 v;
#pragma unroll
    for (int j = 0; j < 8; ++j) v[j] = tile[cc + j][r];
    *(ushort8*)&op[(size_t)(c0 + r) * 2048 + r0 + cc] = v;
  }
}

// ---- GEMM: C[8192x2048] = A[8192x2048] * S (S symmetric), 256^2 tile, 8 waves ----
#define MFMA32 __builtin_amdgcn_mfma_f32_32x32x16_bf16

template <int EPI>
__global__ __launch_bounds__(512, 2)
void gemm256(const unsigned short* __restrict__ A, const unsigned short* __restrict__ S,
             unsigned short* __restrict__ Cb, const float* __restrict__ H,
             float* __restrict__ sums) {
  __shared__ __align__(16) char lds[131072];  // buf0 @0, buf1 @65536; B-region +32768
  const int bid = blockIdx.x;
  const int swz = (bid & 7) * 32 + (bid >> 3);      // XCD-bijective (256 % 8 == 0)
  const int bm = swz >> 3, bn = swz & 7;
  const int tid = threadIdx.x;
  const int lane = tid & 63, wave = tid >> 6;
  const int wr = wave >> 2, wc = wave & 3;          // 2 x 4 wave grid
  const int l31 = lane & 31, hi = lane >> 5;

  const unsigned short* gA = A + (size_t)bm * 256 * 2048;
  const unsigned short* gB = S + (size_t)bn * 256 * 2048;

  // staging: 16B slot ps = tid + i*512; row = ps>>3; global col16 = (ps&7)^(row&7)
  const int row0 = tid >> 3;
  const int slot = (tid & 7) ^ (row0 & 7);

  auto stageA = [&](int kt, int buf) {
    char* lc = lds + buf * 65536;
    const size_t ko = (size_t)kt * 64 + slot * 8;
#pragma unroll
    for (int i = 0; i < 4; ++i)
      gld_lds16(gA + (size_t)(row0 + i * 64) * 2048 + ko,
                (unsigned short*)(lc + (tid + i * 512) * 16));
  };
  auto stageB = [&](int kt, int buf) {
    char* lc = lds + buf * 65536 + 32768;
    const size_t ko = (size_t)kt * 64 + slot * 8;
#pragma unroll
    for (int i = 0; i < 4; ++i)
      gld_lds16(gB + (size_t)(row0 + i * 64) * 2048 + ko,
                (unsigned short*)(lc + (tid + i * 512) * 16));
  };

  // 32x32x16 fragment read bases (row-major-K64 LDS, XOR-swizzled 16B slots).
  // A frag (m,ks), lane l: row = wr*128 + m*32 + (l&31), k = ks*16 + (l>>5)*8
  // byte = row*128 + ((k>>3 ^ (row&7))<<4); ks/lane part folded into off[ks], m into imm.
  int off[4];
#pragma unroll
  for (int ks = 0; ks < 4; ++ks)
    off[ks] = ((ks ^ ((lane >> 1) & 3)) << 5) | ((hi ^ (lane & 1)) << 4);
  const LDS_SPACE char* aB[4];
  const LDS_SPACE char* bB[4];
#pragma unroll
  for (int ks = 0; ks < 4; ++ks) {
    aB[ks] = (const LDS_SPACE char*)lds + wr * 16384 + l31 * 128 + off[ks];
    bB[ks] = (const LDS_SPACE char*)lds + 32768 + wc * 8192 + l31 * 128 + off[ks];
  }

  f32x16 acc[4][2];
#pragma unroll
  for (int m = 0; m < 4; ++m)
#pragma unroll
    for (int n = 0; n < 2; ++n)
#pragma unroll
      for (int j = 0; j < 16; ++j) acc[m][n][j] = 0.f;

  bf16x8 a0[2][4], a2[4], a3[4], b0[4], b1[4];

  stageA(0, 0); stageB(0, 0);

  for (int t = 0; t < 32; ++t) {
    // boundary: publish tile-t staging (issued last iteration) to all waves
    VMC(0);
    BAR();
    const int bufOff = (t & 1) << 16;

    // issue a0 (m0,m1) + b0 (n0): 12 reads
#pragma unroll
    for (int m = 0; m < 2; ++m)
#pragma unroll
      for (int ks = 0; ks < 4; ++ks)
        a0[m][ks] = ds_read128o(aB[ks] + bufOff, m * 4096);
#pragma unroll
    for (int ks = 0; ks < 4; ++ks)
      b0[ks] = ds_read128o(bB[ks] + bufOff, 0);

    // stage next tile into the other buffer (drained at next boundary)
    if (t < 31) { stageA(t + 1, (t + 1) & 1); stageB(t + 1, (t + 1) & 1); }

    LGKM(0); SB0();            // a0,b0 ready

    // issue b1 (n1) + a2 (m2) under QLL
#pragma unroll
    for (int ks = 0; ks < 4; ++ks)
      b1[ks] = ds_read128o(bB[ks] + bufOff, 4096);
#pragma unroll
    for (int ks = 0; ks < 4; ++ks)
      a2[ks] = ds_read128o(aB[ks] + bufOff, 8192);

    PRIO1();                   // QLL: m0,1 x n0
#pragma unroll
    for (int ks = 0; ks < 4; ++ks) {
      acc[0][0] = MFMA32(a0[0][ks], b0[ks], acc[0][0], 0, 0, 0);
      acc[1][0] = MFMA32(a0[1][ks], b0[ks], acc[1][0], 0, 0, 0);
    }
    PRIO0();
    LGKM(4); SB0();            // b1 ready (a2 in flight)
    PRIO1();                   // QLH: m0,1 x n1
#pragma unroll
    for (int ks = 0; ks < 4; ++ks) {
      acc[0][1] = MFMA32(a0[0][ks], b1[ks], acc[0][1], 0, 0, 0);
      acc[1][1] = MFMA32(a0[1][ks], b1[ks], acc[1][1], 0, 0, 0);
    }
    PRIO0();

    // issue a3 (m3) under Q2
#pragma unroll
    for (int ks = 0; ks < 4; ++ks)
      a3[ks] = ds_read128o(aB[ks] + bufOff, 12288);

    LGKM(4); SB0();            // a2 ready (a3 in flight)
    PRIO1();                   // m2 x n0,n1
#pragma unroll
    for (int ks = 0; ks < 4; ++ks) {
      acc[2][0] = MFMA32(a2[ks], b0[ks], acc[2][0], 0, 0, 0);
      acc[2][1] = MFMA32(a2[ks], b1[ks], acc[2][1], 0, 0, 0);
    }
    PRIO0();
    LGKM(0); SB0();            // a3 ready
    PRIO1();                   // m3 x n0,n1
#pragma unroll
    for (int ks = 0; ks < 4; ++ks) {
      acc[3][0] = MFMA32(a3[ks], b0[ks], acc[3][0], 0, 0, 0);
      acc[3][1] = MFMA32(a3[ks], b1[ks], acc[3][1], 0, 0, 0);
    }
    PRIO0();
  }

  // ---- epilogue: 32x32 C/D: col = lane&31, row = (j&3) + 8*(j>>2) + 4*(lane>>5)
  float ssum = 0.f;
#pragma unroll
  for (int m = 0; m < 4; ++m) {
#pragma unroll
    for (int n = 0; n < 2; ++n) {
      const int col = bn * 256 + wc * 64 + n * 32 + l31;
#pragma unroll
      for (int j = 0; j < 16; ++j) {
        const int gr = bm * 256 + wr * 128 + m * 32 + (j & 3) + 8 * (j >> 2) + 4 * hi;
        const float v = acc[m][n][j];
        if (EPI == 1) {
          const int ii = gr & 2047;
          float o = 0.f;
          if (ii < 2047 && col < 2047)
            o = v / H[((size_t)(gr >> 11) * 2047 + ii) * 2047 + col];
          Cb[(size_t)gr * 2048 + col] = f2b(o);
        } else {
          Cb[(size_t)gr * 2048 + col] = f2b(v);
          if (EPI == 2) ssum += v;
        }
      }
    }
  }
  if (EPI == 2) {
#pragma unroll
    for (int off2 = 32; off2 > 0; off2 >>= 1) ssum += __shfl_xor(ssum, off2);
    if (lane == 0) atomicAdd(&sums[bm >> 3], ssum);
  }
}

// ---- final: un-pad, homogeneous correction, mode->layer mix ----
__global__ __launch_bounds__(256)
void final_kernel(const unsigned short* __restrict__ T5, const float* __restrict__ homsol,
                  const float* __restrict__ hm, const float* __restrict__ Cm2l,
                  const float* __restrict__ sums, float* __restrict__ out) {
  const int p = blockIdx.x * 256 + threadIdx.x;
  if (p >= 2049 * 2049) return;
  const int x = p / 2049, y = p - x * 2049;
  const bool interior = (x >= 1) && (x <= 2047) && (y >= 1) && (y <= 2047);
  float pm[4];
#pragma unroll
  for (int m = 0; m < 4; ++m) {
    float inner = 0.f;
    if (interior) inner = b2f(T5[(size_t)m * 4194304u + (size_t)(x - 1) * 2048 + (y - 1)]);
    const float alpha = -(sums[m] * (1.0f / 4194304.0f)) / hm[m];
    pm[m] = inner + alpha * homsol[(size_t)m * 4198401u + p];
  }
#pragma unroll
  for (int l = 0; l < 4; ++l) {
    out[(size_t)l * 4198401u + p] =
        Cm2l[l * 4 + 0] * pm[0] + Cm2l[l * 4 + 1] * pm[1] +
        Cm2l[l * 4 + 2] * pm[2] + Cm2l[l * 4 + 3] * pm[3];
  }
}

extern "C" void kernel_launch(void* const* d_in, const int* in_sizes, int n_in,
                              void* d_out, int out_size, void* d_ws, size_t ws_size,
                              hipStream_t stream) {
  const float* q     = (const float*)d_in[0];   // [4,2047,2047]
  const float* Cl2m  = (const float*)d_in[1];   // [4,4]
  const float* Cm2l  = (const float*)d_in[2];   // [4,4]
  const float* H     = (const float*)d_in[3];   // [4,2047,2047]
  const float* hom   = (const float*)d_in[4];   // [4,2049,2049]
  const float* hmean = (const float*)d_in[5];   // [4]
  float* out = (float*)d_out;

  char* ws = (char*)d_ws;
  unsigned short* P  = (unsigned short*)ws;                    // 33,554,432 B
  unsigned short* Q  = (unsigned short*)(ws + 33554432u);      // 33,554,432 B
  unsigned short* Sb = (unsigned short*)(ws + 67108864u);      //  8,388,608 B
  float* sums        = (float*)(ws + 75497472u);               //        16 B

  dst_kernel<<<16384, 256, 0, stream>>>(Sb);
  mix_kernel<<<16384, 256, 0, stream>>>(q, Cl2m, P);
  hipMemsetAsync(sums, 0, 16, stream);

  // Q1 = P * S            (DST along y)
  gemm256<0><<<256, 512, 0, stream>>>(P, Sb, Q, nullptr, nullptr);
  transpose_bf16<<<dim3(32, 32, 4), 256, 0, stream>>>(Q, P);
  // Q2 = (P * S) / H      (DST along x; H symmetric)
  gemm256<1><<<256, 512, 0, stream>>>(P, Sb, Q, H, nullptr);
  // P2 = Q2 * S           (inverse DST step 1)
  gemm256<0><<<256, 512, 0, stream>>>(Q, Sb, P, nullptr, nullptr);
  transpose_bf16<<<dim3(32, 32, 4), 256, 0, stream>>>(P, Q);
  // T5 = Q3 * S (+ per-mode sum for mean correction)
  gemm256<2><<<256, 512, 0, stream>>>(Q, Sb, P, nullptr, sums);

  final_kernel<<<16401, 256, 0, stream>>>(P, hom, hmean, Cm2l, sums, out);
}

// Round 6
// 328.190 us; speedup vs baseline: 1.2516x; 1.2034x over previous
//
#include <hip/hip_runtime.h>

// DST-I spectral Helmholtz solver, NZ=4, NX=NY=2048.
// Even/odd mirror-fold: S[2046-i][j] = (-1)^j S[i][j]  =>  each M x 2048 x 2048 GEMM
// becomes two M x 1024 x 1024 GEMMs (E-part -> even cols, O-part -> odd cols).
// B-tables are generated transposed with the fold's K-order baked in.

typedef __attribute__((ext_vector_type(8))) short bf16x8;
typedef __attribute__((ext_vector_type(4))) float f32x4;
typedef __attribute__((ext_vector_type(8))) unsigned short ushort8;

#define LDS_SPACE __attribute__((address_space(3)))
#define GLB_SPACE __attribute__((address_space(1)))

__device__ __forceinline__ void gld_lds16(const unsigned short* g, unsigned short* l) {
  __builtin_amdgcn_global_load_lds((const GLB_SPACE void*)g, (LDS_SPACE void*)l, 16, 0, 0);
}

__device__ __forceinline__ bf16x8 ds_read128(const void* p) {
  bf16x8 r;
  const LDS_SPACE char* lp = (const LDS_SPACE char*)p;
  asm volatile("ds_read_b128 %0, %1" : "=v"(r) : "v"(lp));
  return r;
}

__device__ __forceinline__ unsigned short f2b(float f) {
  union { float f; unsigned u; } v; v.f = f;
  unsigned r = (v.u + 0x7fffu + ((v.u >> 16) & 1u)) >> 16;  // RNE
  return (unsigned short)r;
}
__device__ __forceinline__ float b2f(unsigned short u) {
  union { unsigned u; float f; } v; v.u = ((unsigned)u) << 16;
  return v.f;
}

#define LGKM(N) asm volatile("s_waitcnt lgkmcnt(" #N ")" ::: "memory")
#define VMC(N)  asm volatile("s_waitcnt vmcnt(" #N ")" ::: "memory")
#define BAR()   __builtin_amdgcn_s_barrier()
#define SB0()   __builtin_amdgcn_sched_barrier(0)
#define PRIO1() __builtin_amdgcn_s_setprio(1)
#define PRIO0() __builtin_amdgcn_s_setprio(0)

// ---- tables: T[tbl][n][k] (transposed: row n = out col, col k = K idx), bf16 ----
// tbl 0: TE1 (natural fold, even cols)  1: TO1 (natural fold, odd cols)
// tbl 2: TE3 (interleaved fold, even)   3: TO3 (interleaved fold, odd)
__global__ __launch_bounds__(256)
void tables_kernel(unsigned short* __restrict__ T) {
  const int idx = blockIdx.x * 256 + threadIdx.x;     // < 4*1024*1024
  const int tbl = idx >> 20, n = (idx >> 10) & 1023, k = idx & 1023;
  int a;
  if (tbl < 2) a = k;                                  // natural pair-rep order
  else a = (k < 512) ? 2 * k : (k < 1023 ? 2 * (k - 512) + 1 : 1023);
  const int cp1 = (tbl & 1) ? 2 * n + 2 : 2 * n + 1;   // j_true+1
  const int ph = ((a + 1) * cp1) & 4095;               // exact phase mod 2*pi
  const float v = 0.03125f * sinf(3.14159265358979323846f * (float)ph * (1.0f / 2048.0f));
  T[idx] = f2b(v);
}

// ---- mix + natural fold along y: AE/AO [4*2048 x 1024] bf16 ----
__global__ __launch_bounds__(256)
void mix_fold(const float* __restrict__ q, const float* __restrict__ Cl2m,
              unsigned short* __restrict__ AE, unsigned short* __restrict__ AO) {
  const int idx = blockIdx.x * 256 + threadIdx.x;     // < 2048*1024
  const int x = idx >> 10, u = idx & 1023;
  float c[16];
#pragma unroll
  for (int i = 0; i < 16; ++i) c[i] = Cl2m[i];
  float fe[4] = {0.f, 0.f, 0.f, 0.f}, fo[4] = {0.f, 0.f, 0.f, 0.f};
  if (x < 2047) {
#pragma unroll
    for (int l = 0; l < 4; ++l) {
      const size_t base = ((size_t)l * 2047 + x) * 2047;
      const float qa = q[base + u];
      const float qb = (u < 1023) ? q[base + 2046 - u] : 0.f;
      const float E = (u == 1023) ? qa : qa + qb;
      const float O = (u == 1023) ? 0.f : qa - qb;
#pragma unroll
      for (int m = 0; m < 4; ++m) { fe[m] += c[m * 4 + l] * E; fo[m] += c[m * 4 + l] * O; }
    }
  }
#pragma unroll
  for (int m = 0; m < 4; ++m) {
    AE[((size_t)m * 2048 + x) * 1024 + u] = f2b(fe[m]);
    AO[((size_t)m * 2048 + x) * 1024 + u] = f2b(fo[m]);
  }
}

// ---- transpose + fold (per mode): out[c][u] = in[r1(u)][c] +/- in[r2(u)][c] ----
// MAP 0: natural rows (u, 2046-u).  MAP 1: interleaved rows (within-half pairs).
template <int MAP>
__global__ __launch_bounds__(256)
void tfold(const unsigned short* __restrict__ in, unsigned short* __restrict__ outE,
           unsigned short* __restrict__ outO) {
  __shared__ unsigned short t1[64][72];
  __shared__ unsigned short t2[64][72];
  const size_t ib = (size_t)blockIdx.z * (2048u * 2048u);
  const size_t ob = (size_t)blockIdx.z * (2048u * 1024u);
  const int c0 = blockIdx.x * 64, u0 = blockIdx.y * 64;
  const int t = threadIdx.x;
  const int rr = t >> 3, cc = (t & 7) * 8;
#pragma unroll
  for (int ch = 0; ch < 2; ++ch) {
    const int r = ch * 32 + rr, u = u0 + r;
    const int r1 = (MAP == 0) ? u : (u < 512 ? u : 1024 + (u - 512));
    const int r2 = (MAP == 0) ? 2046 - u : (u < 512 ? 1023 - u : 2046 - (u - 512));
    ushort8 v1 = *(const ushort8*)&in[ib + (size_t)r1 * 2048 + c0 + cc];
    ushort8 v2 = *(const ushort8*)&in[ib + (size_t)r2 * 2048 + c0 + cc];
#pragma unroll
    for (int j = 0; j < 8; ++j) { t1[r][cc + j] = v1[j]; t2[r][cc + j] = v2[j]; }
  }
  __syncthreads();
#pragma unroll
  for (int ch = 0; ch < 2; ++ch) {
    const int r = ch * 32 + rr;       // output c-offset within tile
    ushort8 vE, vO;
#pragma unroll
    for (int j = 0; j < 8; ++j) {
      const int uu = u0 + cc + j;
      const float a = b2f(t1[cc + j][r]);
      const float b = b2f(t2[cc + j][r]);
      vE[j] = f2b((uu == 1023) ? a : a + b);
      vO[j] = f2b((uu == 1023) ? 0.f : a - b);
    }
    const size_t o = ob + (size_t)(c0 + r) * 1024 + u0 + cc;
    *(ushort8*)&outE[o] = vE;
    *(ushort8*)&outO[o] = vO;
  }
}

// ---- column fold over interleaved axis (no transpose): pre-G3 ----
__global__ __launch_bounds__(256)
void fold_cols(const unsigned short* __restrict__ R, unsigned short* __restrict__ AE,
               unsigned short* __restrict__ AO) {
  const int idx = blockIdx.x * 256 + threadIdx.x;     // < 8192*1024
  const int row = idx >> 10, u = idx & 1023;
  const int c1 = (u < 512) ? u : (u < 1023 ? 512 + u : 1535);
  const int c2 = (u < 512) ? 1023 - u : (u < 1023 ? 2558 - u : 1535);
  const float a = b2f(R[(size_t)row * 2048 + c1]);
  const float b = b2f(R[(size_t)row * 2048 + c2]);
  AE[(size_t)row * 1024 + u] = f2b((u == 1023) ? a : a + b);
  AO[(size_t)row * 1024 + u] = f2b((u == 1023) ? 0.f : a - b);
}

// ---- GEMM: C_half[8192x1024] = A_half[8192x1024] * T_half^T, halves packed in one grid ----
// EPI 0: write bf16. EPI 1: divide by H (spectral indices decoded), write bf16.
// EPI 2: write bf16 + per-mode sum.
#define MFMA_BF16 __builtin_amdgcn_mfma_f32_16x16x32_bf16

template <int EPI>
__global__ __launch_bounds__(512, 2)
void gemm_eo(const unsigned short* __restrict__ A, const unsigned short* __restrict__ T,
             unsigned short* __restrict__ Cb, const float* __restrict__ H,
             float* __restrict__ sums) {
  __shared__ __align__(16) char lds[131072];  // buf0 @0, buf1 @65536; B-region +32768
  const int bid = blockIdx.x;
  const int swz = (bid & 7) * 32 + (bid >> 3);      // XCD-bijective (256 % 8 == 0)
  const int h = swz & 1;                            // 0: even(E), 1: odd(O)
  const int bn = (swz >> 1) & 3, bm = swz >> 3;
  const int tid = threadIdx.x;
  const int lane = tid & 63, wave = tid >> 6;
  const int wr = wave >> 2, wc = wave & 3;          // 2 x 4 wave grid
  const int lr = lane & 15, kg = lane >> 4;

  const unsigned short* gA = A + (size_t)h * 8388608u + (size_t)bm * 256 * 1024;
  const unsigned short* gB = T + (size_t)h * 1048576u + (size_t)bn * 256 * 1024;

  // staging: 16B slot ps = tid + i*512; row = ps>>3; k-col16 = (ps&7)^(row&7)
  const int row0 = tid >> 3;
  const int slot = (tid & 7) ^ (row0 & 7);

  auto stage = [&](int kt, int c) {
    char* lc = lds + c * 65536;
    const size_t ko = (size_t)kt * 64 + slot * 8;
#pragma unroll
    for (int i = 0; i < 4; ++i)
      gld_lds16(gA + (size_t)(row0 + i * 64) * 1024 + ko,
                (unsigned short*)(lc + (tid + i * 512) * 16));
#pragma unroll
    for (int i = 0; i < 4; ++i)
      gld_lds16(gB + (size_t)(row0 + i * 64) * 1024 + ko,
                (unsigned short*)(lc + 32768 + (tid + i * 512) * 16));
  };

  f32x4 acc[8][4];
#pragma unroll
  for (int m = 0; m < 8; ++m)
#pragma unroll
    for (int n = 0; n < 4; ++n) acc[m][n] = (f32x4){0.f, 0.f, 0.f, 0.f};

  stage(0, 0);
  stage(1, 1);

  const int arow = wr * 128 + lr;
  const int brow = wc * 64 + lr;
  const int x7 = lr & 7;

  for (int t = 0; t < 16; ++t) {
    const char* la = lds + (t & 1) * 65536;
    const char* lb = la + 32768;
    if (t < 15) { VMC(8); } else { VMC(0); }
    BAR();   // all waves' tile-t loads landed

    bf16x8 al[4][2], ah[4][2], bl[2][2], bh[2][2];

    // ==== E1: issue al(8)+bl(4) -> barrier -> wait -> MFMA Q1 (m0-3, n0-1)
#pragma unroll
    for (int m = 0; m < 4; ++m)
#pragma unroll
      for (int ks = 0; ks < 2; ++ks)
        al[m][ks] = ds_read128(la + (arow + m * 16) * 128 + (((ks * 4 + kg) ^ x7) << 4));
#pragma unroll
    for (int n = 0; n < 2; ++n)
#pragma unroll
      for (int ks = 0; ks < 2; ++ks)
        bl[n][ks] = ds_read128(lb + (brow + n * 16) * 128 + (((ks * 4 + kg) ^ x7) << 4));
    BAR();
    LGKM(0); SB0();
    PRIO1();
#pragma unroll
    for (int ks = 0; ks < 2; ++ks)
#pragma unroll
      for (int m = 0; m < 4; ++m)
#pragma unroll
        for (int n = 0; n < 2; ++n)
          acc[m][n] = MFMA_BF16(al[m][ks], bl[n][ks], acc[m][n], 0, 0, 0);
    PRIO0();

    // ==== E2: issue bh(4) then ah(8) -> barrier -> wait bh -> MFMA Q2 (m0-3, n2-3)
#pragma unroll
    for (int n = 0; n < 2; ++n)
#pragma unroll
      for (int ks = 0; ks < 2; ++ks)
        bh[n][ks] = ds_read128(lb + (brow + (n + 2) * 16) * 128 + (((ks * 4 + kg) ^ x7) << 4));
#pragma unroll
    for (int m = 0; m < 4; ++m)
#pragma unroll
      for (int ks = 0; ks < 2; ++ks)
        ah[m][ks] = ds_read128(la + (arow + (m + 4) * 16) * 128 + (((ks * 4 + kg) ^ x7) << 4));
    BAR();
    LGKM(8); SB0();
    PRIO1();
#pragma unroll
    for (int ks = 0; ks < 2; ++ks)
#pragma unroll
      for (int m = 0; m < 4; ++m)
#pragma unroll
        for (int n = 0; n < 2; ++n)
          acc[m][n + 2] = MFMA_BF16(al[m][ks], bh[n][ks], acc[m][n + 2], 0, 0, 0);
    PRIO0();

    // ==== E3: barrier -> wait ah -> MFMA Q3+Q4 (m4-7, all n)
    BAR();
    LGKM(0); SB0();
    PRIO1();
#pragma unroll
    for (int ks = 0; ks < 2; ++ks)
#pragma unroll
      for (int m = 0; m < 4; ++m)
#pragma unroll
        for (int n = 0; n < 2; ++n)
          acc[m + 4][n + 2] = MFMA_BF16(ah[m][ks], bh[n][ks], acc[m + 4][n + 2], 0, 0, 0);
#pragma unroll
    for (int ks = 0; ks < 2; ++ks)
#pragma unroll
      for (int m = 0; m < 4; ++m)
#pragma unroll
        for (int n = 0; n < 2; ++n)
          acc[m + 4][n] = MFMA_BF16(ah[m][ks], bl[n][ks], acc[m + 4][n], 0, 0, 0);
    PRIO0();

    if (t < 14) stage(t + 2, t & 1);
  }

  LGKM(0); VMC(0);

  // ---- epilogue: fragment row = kg*4+j, col = lr ----
  float ssum = 0.f;
#pragma unroll
  for (int m = 0; m < 8; ++m) {
#pragma unroll
    for (int n = 0; n < 4; ++n) {
      const int coln = bn * 256 + wc * 64 + n * 16 + lr;   // col within half
      const int col = h * 1024 + coln;                     // storage col in [0,2048)
#pragma unroll
      for (int j = 0; j < 4; ++j) {
        const int gr = bm * 256 + wr * 128 + m * 16 + kg * 4 + j;
        const float v = acc[m][n][j];
        if (EPI == 1) {
          const int jint = gr & 2047;
          const int j_true = 2 * (jint & 1023) + (jint >> 10);
          const int i_true = 2 * coln + h;
          float o = 0.f;
          if (i_true < 2047 && j_true < 2047)
            o = v / H[((size_t)(gr >> 11) * 2047 + i_true) * 2047 + j_true];
          Cb[(size_t)gr * 2048 + col] = f2b(o);
        } else {
          Cb[(size_t)gr * 2048 + col] = f2b(v);
          if (EPI == 2) ssum += v;
        }
      }
    }
  }
  if (EPI == 2) {
#pragma unroll
    for (int off = 32; off > 0; off >>= 1) ssum += __shfl_xor(ssum, off);
    if (lane == 0) atomicAdd(&sums[bm >> 3], ssum);
  }
}

// ---- final: de-interleave, homogeneous correction, mode->layer mix ----
__global__ __launch_bounds__(256)
void final_kernel(const unsigned short* __restrict__ V, const float* __restrict__ homsol,
                  const float* __restrict__ hm, const float* __restrict__ Cm2l,
                  const float* __restrict__ sums, float* __restrict__ out) {
  const int p = blockIdx.x * 256 + threadIdx.x;
  if (p >= 2049 * 2049) return;
  const int x = p / 2049, y = p - x * 2049;
  const bool interior = (x >= 1) && (x <= 2047) && (y >= 1) && (y <= 2047);
  int row = 0, col = 0;
  if (interior) {
    const int xt = x - 1, yt = y - 1;
    row = (xt & 1) ? 1024 + (xt >> 1) : (xt >> 1);
    col = (yt & 1) ? 1024 + (yt >> 1) : (yt >> 1);
  }
  float pm[4];
#pragma unroll
  for (int m = 0; m < 4; ++m) {
    float inner = 0.f;
    if (interior) inner = b2f(V[((size_t)m * 2048 + row) * 2048 + col]);
    const float alpha = -(sums[m] * (1.0f / 4194304.0f)) / hm[m];
    pm[m] = inner + alpha * homsol[(size_t)m * 4198401u + p];
  }
#pragma unroll
  for (int l = 0; l < 4; ++l) {
    out[(size_t)l * 4198401u + p] =
        Cm2l[l * 4 + 0] * pm[0] + Cm2l[l * 4 + 1] * pm[1] +
        Cm2l[l * 4 + 2] * pm[2] + Cm2l[l * 4 + 3] * pm[3];
  }
}

extern "C" void kernel_launch(void* const* d_in, const int* in_sizes, int n_in,
                              void* d_out, int out_size, void* d_ws, size_t ws_size,
                              hipStream_t stream) {
  const float* q     = (const float*)d_in[0];   // [4,2047,2047]
  const float* Cl2m  = (const float*)d_in[1];   // [4,4]
  const float* Cm2l  = (const float*)d_in[2];   // [4,4]
  const float* H     = (const float*)d_in[3];   // [4,2047,2047]
  const float* hom   = (const float*)d_in[4];   // [4,2049,2049]
  const float* hmean = (const float*)d_in[5];   // [4]
  float* out = (float*)d_out;

  char* ws = (char*)d_ws;
  unsigned short* Tb = (unsigned short*)ws;                    //  8 MB: TE1|TO1|TE3|TO3
  unsigned short* Aslot = (unsigned short*)(ws + 8388608u);    // 32 MB: [E half | O half]
  unsigned short* Bslot = (unsigned short*)(ws + 41943040u);   // 32 MB
  float* sums        = (float*)(ws + 75497472u);               // 16 B
  unsigned short* AO = Aslot + 8388608u;                       // O-half base

  tables_kernel<<<16384, 256, 0, stream>>>(Tb);
  mix_fold<<<8192, 256, 0, stream>>>(q, Cl2m, Aslot, AO);
  hipMemsetAsync(sums, 0, 16, stream);

  const dim3 tg(32, 16, 4);
  // G1: Q1 = fold(P) x S  (DST along y) -> [Ce|Co] cols
  gemm_eo<0><<<256, 512, 0, stream>>>(Aslot, Tb, Bslot, nullptr, nullptr);
  // transpose + natural fold over x
  tfold<0><<<tg, 256, 0, stream>>>(Bslot, Aslot, AO);
  // G2: R = (fold(Q1^T) x S) / H  (DST along x, spectral divide)
  gemm_eo<1><<<256, 512, 0, stream>>>(Aslot, Tb, Bslot, H, nullptr);
  // interleaved column fold over spectral-x
  fold_cols<<<32768, 256, 0, stream>>>(Bslot, Aslot, AO);
  // G3: U = fold(R) x S  (inverse DST step 1) -- interleaved-fold tables
  gemm_eo<0><<<256, 512, 0, stream>>>(Aslot, Tb + 2097152u, Bslot, nullptr, nullptr);
  // transpose + interleaved fold over spectral-y
  tfold<1><<<tg, 256, 0, stream>>>(Bslot, Aslot, AO);
  // G4: V = fold(U^T) x S (+ per-mode sum)
  gemm_eo<2><<<256, 512, 0, stream>>>(Aslot, Tb + 2097152u, Bslot, nullptr, sums);

  final_kernel<<<16401, 256, 0, stream>>>(Bslot, hom, hmean, Cm2l, sums, out);
}